// Round 1
// 1058.237 us; speedup vs baseline: 1.2939x; 1.2939x over previous
//
#include <hip/hip_runtime.h>

// ---------------- problem constants ----------------
#define N_NODES 100000
#define N_EDGES 1600000
#define DN 128
#define DE 48
#define HDIM 256
#define IN1 176            // DN + DE
#define K1 352             // 2*IN1  (concat [h | h_neigh] for layer 1)
#define K2 512             // 2*HDIM (concat [h1 | h_neigh] for layer 2)
#define NPAD 100096        // 782 * 128 (GEMM row padding; also 391*256 scan width)
#define NB 391             // scan blocks = NPAD/256

typedef __bf16 bf16;
typedef __bf16 bf16x2 __attribute__((ext_vector_type(2)));
typedef __bf16 bf16x8 __attribute__((ext_vector_type(8)));
typedef float  f32x4  __attribute__((ext_vector_type(4)));

// ---------------- workspace layout (bytes) ----------------
#define O_DEG  0UL                      // NPAD int
#define O_ROW  400384UL                 // NPAD int (rowptr)
#define O_CUR  800768UL                 // NPAD int (fill cursor)
#define O_PRE  1201152UL                // NPAD int (block-local prefix)
#define O_PART 1601536UL                // 512 int (block partials)
#define O_CSR  1603584UL                // E int2 (src, eid) = 12.8 MB
#define O_H1   14403584UL               // NPAD x 352 bf16 = 70.5 MB
#define O_H2   84871168UL               // NPAD x 512 bf16 = 102.5 MB
#define O_W1   187369472UL              // 256 x 352 bf16
#define O_W2   187549696UL              // 256 x 512 bf16; end ~188 MB

__device__ __forceinline__ float bf_lo(unsigned u) { return __uint_as_float(u << 16); }
__device__ __forceinline__ float bf_hi(unsigned u) { return __uint_as_float(u & 0xffff0000u); }
__device__ __forceinline__ unsigned bf_pk(float a, float b) {
    union { bf16x2 v; unsigned u; } t;
    t.v.x = (bf16)a; t.v.y = (bf16)b;
    return t.u;
}

// ---------------- weight prep: bf16, transposed to [n][k], self/neigh stacked in k ----------------
__global__ void k_prep_weights(const float* __restrict__ Ws1, const float* __restrict__ Wn1,
                               const float* __restrict__ Ws2, const float* __restrict__ Wn2,
                               bf16* __restrict__ Wt1, bf16* __restrict__ Wt2) {
    int tid = blockIdx.x * 256 + threadIdx.x;
    if (tid < HDIM * K1) {
        int n = tid / K1, k = tid - n * K1;
        float v = (k < IN1) ? Ws1[k * HDIM + n] : Wn1[(k - IN1) * HDIM + n];
        Wt1[n * K1 + k] = (bf16)v;
    } else {
        int t2 = tid - HDIM * K1;
        int n = t2 / K2, k = t2 - n * K2;
        float v = (k < HDIM) ? Ws2[k * HDIM + n] : Wn2[(k - HDIM) * HDIM + n];
        Wt2[n * K2 + k] = (bf16)v;
    }
}

// ---------------- CSR build ----------------
__global__ void k_count(const int* __restrict__ dst, int* __restrict__ deg) {
    int e = blockIdx.x * 256 + threadIdx.x;
    if (e < N_EDGES) atomicAdd(&deg[dst[e]], 1);
}

// block-inclusive Hillis-Steele scan over `lds`, returns inclusive prefix of v
template <int NT>
__device__ __forceinline__ int block_scan_inc(int v, int* lds) {
    int tid = threadIdx.x;
    lds[tid] = v;
#pragma unroll
    for (int off = 1; off < NT; off <<= 1) {
        __syncthreads();
        int t = (tid >= off) ? lds[tid - off] : 0;
        __syncthreads();
        lds[tid] += t;
    }
    return lds[tid];
}

__global__ void k_scanA(const int* __restrict__ deg, int* __restrict__ presum,
                        int* __restrict__ part) {
    __shared__ int lds[256];
    int idx = blockIdx.x * 256 + threadIdx.x;
    int v = (idx < N_NODES) ? deg[idx] : 0;
    int inc = block_scan_inc<256>(v, lds);
    presum[idx] = inc - v;
    if (threadIdx.x == 255) part[blockIdx.x] = inc;
}

__global__ void k_scanB(int* __restrict__ part) {
    __shared__ int lds[512];
    int t = threadIdx.x;
    int v = (t < NB) ? part[t] : 0;
    int inc = block_scan_inc<512>(v, lds);
    if (t < NB) part[t] = inc - v;   // exclusive
}

__global__ void k_scanC(const int* __restrict__ presum, const int* __restrict__ part,
                        int* __restrict__ rowptr, int* __restrict__ cursor) {
    int idx = blockIdx.x * 256 + threadIdx.x;
    int v = presum[idx] + part[blockIdx.x];
    if (idx < N_NODES) { rowptr[idx] = v; cursor[idx] = v; }
}

__global__ void k_fill(const int* __restrict__ src, const int* __restrict__ dst,
                       int* __restrict__ cursor, int2* __restrict__ csr) {
    int e = blockIdx.x * 256 + threadIdx.x;   // exact grid
    int p = atomicAdd(&cursor[dst[e]], 1);
    csr[p] = make_int2(src[e], e);
}

// ---------------- aggregation: one wave per node ----------------
// Latency-chain fix: lane i preloads csr[base+c+i] (one coalesced load per
// 64-edge chunk), then shfl-broadcast 8 eids at a time and issue 8 INDEPENDENT
// gathers into distinct regs (load phase separated from accumulate phase so the
// compiler's waitcnt lands after all 8 issue). MLP 1 -> 8 per wave.

// h1 row n, cols 0:128 = fn[n]; cols 128:176 = mean of fe over incoming edges
__global__ void k_agg_edges(const float* __restrict__ fn, const float* __restrict__ fe,
                            const int* __restrict__ rowptr, const int* __restrict__ deg,
                            const int2* __restrict__ csr, bf16* __restrict__ h1) {
    int node = blockIdx.x * 4 + (threadIdx.x >> 6);  // grid 25000 exact
    int lane = threadIdx.x & 63;
    bf16* row = h1 + (size_t)node * K1;
    float2 f = *(const float2*)(fn + (size_t)node * DN + lane * 2);
    *(unsigned*)&row[lane * 2] = bf_pk(f.x, f.y);
    int base = rowptr[node], d = deg[node];
    float s = 0.f;
    for (int c = 0; c < d; c += 64) {
        int nn = min(d - c, 64);
        int myE = (lane < nn) ? csr[base + c + lane].y : 0;
        for (int i = 0; i < nn; i += 8) {
            int e[8];
#pragma unroll
            for (int j = 0; j < 8; ++j) e[j] = __shfl(myE, i + j);
            float v[8];
#pragma unroll
            for (int j = 0; j < 8; ++j) {
                v[j] = 0.f;
                if ((i + j < nn) && (lane < DE))
                    v[j] = fe[(size_t)e[j] * DE + lane];
            }
            s += ((v[0] + v[1]) + (v[2] + v[3])) + ((v[4] + v[5]) + (v[6] + v[7]));
        }
    }
    float r = 1.0f / (float)max(d, 1);
    if (lane < DE) row[DN + lane] = (bf16)(s * r);
}

// h1 cols 176:352 = mean over incoming edges of h1[src, 0:176]
// 176 bf16 cols = 44 lanes x uint2 (one 8B load/edge instead of two b32 loads)
__global__ void k_agg1(const int* __restrict__ rowptr, const int* __restrict__ deg,
                       const int2* __restrict__ csr, bf16* __restrict__ h1) {
    int node = blockIdx.x * 4 + (threadIdx.x >> 6);
    int lane = threadIdx.x & 63;
    int base = rowptr[node], d = deg[node];
    float s0 = 0.f, s1 = 0.f, s2 = 0.f, s3 = 0.f;
    for (int c = 0; c < d; c += 64) {
        int nn = min(d - c, 64);
        int mySv = (lane < nn) ? csr[base + c + lane].x : 0;
        for (int i = 0; i < nn; i += 8) {
            int sv[8];
#pragma unroll
            for (int j = 0; j < 8; ++j) sv[j] = __shfl(mySv, i + j);
            uint2 u[8];
#pragma unroll
            for (int j = 0; j < 8; ++j) {
                u[j] = make_uint2(0u, 0u);
                if ((i + j < nn) && (lane < 44))
                    u[j] = ((const uint2*)(h1 + (size_t)sv[j] * K1))[lane];
            }
#pragma unroll
            for (int j = 0; j < 8; ++j) {
                s0 += bf_lo(u[j].x); s1 += bf_hi(u[j].x);
                s2 += bf_lo(u[j].y); s3 += bf_hi(u[j].y);
            }
        }
    }
    float r = 1.0f / (float)max(d, 1);
    if (lane < 44) {
        uint2 o;
        o.x = bf_pk(s0 * r, s1 * r);
        o.y = bf_pk(s2 * r, s3 * r);
        ((uint2*)(h1 + (size_t)node * K1 + IN1))[lane] = o;
    }
}

// h2 cols 256:512 = mean over incoming edges of h2[src, 0:256]
__global__ void k_agg2(const int* __restrict__ rowptr, const int* __restrict__ deg,
                       const int2* __restrict__ csr, bf16* __restrict__ h2) {
    int node = blockIdx.x * 4 + (threadIdx.x >> 6);
    int lane = threadIdx.x & 63;
    int base = rowptr[node], d = deg[node];
    float s0 = 0.f, s1 = 0.f, s2 = 0.f, s3 = 0.f;
    for (int c = 0; c < d; c += 64) {
        int nn = min(d - c, 64);
        int mySv = (lane < nn) ? csr[base + c + lane].x : 0;
        for (int i = 0; i < nn; i += 8) {
            int sv[8];
#pragma unroll
            for (int j = 0; j < 8; ++j) sv[j] = __shfl(mySv, i + j);
            uint2 u[8];
#pragma unroll
            for (int j = 0; j < 8; ++j) {
                u[j] = make_uint2(0u, 0u);
                if (i + j < nn)
                    u[j] = ((const uint2*)(h2 + (size_t)sv[j] * K2))[lane];
            }
#pragma unroll
            for (int j = 0; j < 8; ++j) {
                s0 += bf_lo(u[j].x); s1 += bf_hi(u[j].x);
                s2 += bf_lo(u[j].y); s3 += bf_hi(u[j].y);
            }
        }
    }
    float r = 1.0f / (float)max(d, 1);
    uint2 o;
    o.x = bf_pk(s0 * r, s1 * r);
    o.y = bf_pk(s2 * r, s3 * r);
    ((uint2*)(h2 + (size_t)node * K2 + HDIM))[lane] = o;
}

// ---------------- bf16 MFMA GEMM: C[NPAD,256] = A[NPAD,K] @ Wt^T + bias ----------------
template <bool RELU, typename OT>
__global__ __launch_bounds__(256) void k_gemm(const bf16* __restrict__ A,
                                              const bf16* __restrict__ Wt,
                                              const float* __restrict__ bias,
                                              OT* __restrict__ out,
                                              int Ktiles, int ostride) {
    __shared__ __align__(16) bf16 lA[128 * 40];
    __shared__ __align__(16) bf16 lB[128 * 40];

    const int tid = threadIdx.x;
    const int rowBase = blockIdx.x * 128;
    const int colBase = blockIdx.y * 128;
    const int l = tid & 63, w = tid >> 6;
    const int wr = (w >> 1) * 64, wc = (w & 1) * 64;
    const int lm = l & 15, lq = l >> 4;
    const int K = Ktiles * 32;

    const int srow = tid >> 1;
    const int sko  = (tid & 1) * 16;

    f32x4 acc[4][4] = {};

    for (int kt = 0; kt < Ktiles; ++kt) {
        const int k0 = kt * 32;
        const uint4* pa = (const uint4*)(A  + (size_t)(rowBase + srow) * K + k0 + sko);
        const uint4* pb = (const uint4*)(Wt + (size_t)(colBase + srow) * K + k0 + sko);
        uint4 a0 = pa[0], a1 = pa[1];
        uint4 b0 = pb[0], b1 = pb[1];
        __syncthreads();
        *(uint4*)&lA[srow * 40 + sko]     = a0;
        *(uint4*)&lA[srow * 40 + sko + 8] = a1;
        *(uint4*)&lB[srow * 40 + sko]     = b0;
        *(uint4*)&lB[srow * 40 + sko + 8] = b1;
        __syncthreads();

        bf16x8 af[4], bfr[4];
#pragma unroll
        for (int mi = 0; mi < 4; ++mi)
            af[mi] = *(const bf16x8*)&lA[(wr + mi * 16 + lm) * 40 + lq * 8];
#pragma unroll
        for (int ni = 0; ni < 4; ++ni)
            bfr[ni] = *(const bf16x8*)&lB[(wc + ni * 16 + lm) * 40 + lq * 8];
#pragma unroll
        for (int mi = 0; mi < 4; ++mi)
#pragma unroll
            for (int ni = 0; ni < 4; ++ni)
                acc[mi][ni] = __builtin_amdgcn_mfma_f32_16x16x32_bf16(
                    af[mi], bfr[ni], acc[mi][ni], 0, 0, 0);
    }

#pragma unroll
    for (int ni = 0; ni < 4; ++ni) {
        const int gcol = colBase + wc + ni * 16 + lm;
        const float bv = bias[gcol];
#pragma unroll
        for (int mi = 0; mi < 4; ++mi) {
#pragma unroll
            for (int r = 0; r < 4; ++r) {
                const int grow = rowBase + wr + mi * 16 + lq * 4 + r;
                if (grow < N_NODES) {
                    float v = acc[mi][ni][r] + bv;
                    if (RELU) v = fmaxf(v, 0.0f);
                    out[(size_t)grow * ostride + gcol] = (OT)v;
                }
            }
        }
    }
}

// ---------------- launcher ----------------
extern "C" void kernel_launch(void* const* d_in, const int* in_sizes, int n_in,
                              void* d_out, int out_size, void* d_ws, size_t ws_size,
                              hipStream_t stream) {
    const float* fn  = (const float*)d_in[0];
    const float* fe  = (const float*)d_in[1];
    const int*   src = (const int*)d_in[2];
    const int*   dst = (const int*)d_in[3];
    const float* Ws1 = (const float*)d_in[4];
    const float* Wn1 = (const float*)d_in[5];
    const float* b1  = (const float*)d_in[6];
    const float* Ws2 = (const float*)d_in[7];
    const float* Wn2 = (const float*)d_in[8];
    const float* b2  = (const float*)d_in[9];
    float* out = (float*)d_out;

    char* ws = (char*)d_ws;
    int*  deg    = (int*)(ws + O_DEG);
    int*  rowptr = (int*)(ws + O_ROW);
    int*  cursor = (int*)(ws + O_CUR);
    int*  presum = (int*)(ws + O_PRE);
    int*  part   = (int*)(ws + O_PART);
    int2* csr    = (int2*)(ws + O_CSR);
    bf16* h1  = (bf16*)(ws + O_H1);
    bf16* h2  = (bf16*)(ws + O_H2);
    bf16* Wt1 = (bf16*)(ws + O_W1);
    bf16* Wt2 = (bf16*)(ws + O_W2);

    hipMemsetAsync(deg, 0, (size_t)NPAD * 4, stream);
    hipMemsetAsync((char*)h1 + (size_t)N_NODES * K1 * 2, 0, (size_t)(NPAD - N_NODES) * K1 * 2, stream);
    hipMemsetAsync((char*)h2 + (size_t)N_NODES * K2 * 2, 0, (size_t)(NPAD - N_NODES) * K2 * 2, stream);

    k_prep_weights<<<(HDIM * K1 + HDIM * K2) / 256, 256, 0, stream>>>(Ws1, Wn1, Ws2, Wn2, Wt1, Wt2);

    // CSR build
    k_count<<<(N_EDGES + 255) / 256, 256, 0, stream>>>(dst, deg);
    k_scanA<<<NB, 256, 0, stream>>>(deg, presum, part);
    k_scanB<<<1, 512, 0, stream>>>(part);
    k_scanC<<<NB, 256, 0, stream>>>(presum, part, rowptr, cursor);
    k_fill<<<N_EDGES / 256, 256, 0, stream>>>(src, dst, cursor, csr);

    // layer 1
    k_agg_edges<<<N_NODES / 4, 256, 0, stream>>>(fn, fe, rowptr, deg, csr, h1);
    k_agg1<<<N_NODES / 4, 256, 0, stream>>>(rowptr, deg, csr, h1);
    k_gemm<true, bf16><<<dim3(NPAD / 128, 2), 256, 0, stream>>>(h1, Wt1, b1, h2, K1 / 32, K2);

    // layer 2
    k_agg2<<<N_NODES / 4, 256, 0, stream>>>(rowptr, deg, csr, h2);
    k_gemm<false, float><<<dim3(NPAD / 128, 2), 256, 0, stream>>>(h2, Wt2, b2, out, K2 / 32, HDIM);
}

// Round 2
// 1055.829 us; speedup vs baseline: 1.2969x; 1.0023x over previous
//
#include <hip/hip_runtime.h>

// ---------------- problem constants ----------------
#define N_NODES 100000
#define N_EDGES 1600000
#define DN 128
#define DE 48
#define HDIM 256
#define IN1 176            // DN + DE
#define K1 352             // 2*IN1  (concat [h | h_neigh] for layer 1)
#define K2 512             // 2*HDIM (concat [h1 | h_neigh] for layer 2)
#define NPAD 100096        // 782 * 128 (GEMM row padding; also 391*256 scan width)
#define NB 391             // scan blocks = NPAD/256

typedef __bf16 bf16;
typedef __bf16 bf16x2 __attribute__((ext_vector_type(2)));
typedef __bf16 bf16x8 __attribute__((ext_vector_type(8)));
typedef float  f32x4  __attribute__((ext_vector_type(4)));

// ---------------- workspace layout (bytes) ----------------
#define O_DEG  0UL                      // NPAD int
#define O_ROW  400384UL                 // NPAD int (rowptr)
#define O_CUR  800768UL                 // NPAD int (fill cursor)
#define O_PRE  1201152UL                // NPAD int (block-local prefix)
#define O_PART 1601536UL                // 512 int (block partials)
#define O_CSR  1603584UL                // E int2 (src, eid) = 12.8 MB
#define O_H1   14403584UL               // NPAD x 352 bf16 = 70.5 MB
#define O_H2   84871168UL               // NPAD x 512 bf16 = 102.5 MB
#define O_W1   187369472UL              // 256 x 352 bf16
#define O_W2   187549696UL              // 256 x 512 bf16; end ~188 MB

__device__ __forceinline__ float bf_lo(unsigned u) { return __uint_as_float(u << 16); }
__device__ __forceinline__ float bf_hi(unsigned u) { return __uint_as_float(u & 0xffff0000u); }
__device__ __forceinline__ unsigned bf_pk(float a, float b) {
    union { bf16x2 v; unsigned u; } t;
    t.v.x = (bf16)a; t.v.y = (bf16)b;
    return t.u;
}

// ---------------- weight prep: bf16, transposed to [n][k], self/neigh stacked in k ----------------
__global__ void k_prep_weights(const float* __restrict__ Ws1, const float* __restrict__ Wn1,
                               const float* __restrict__ Ws2, const float* __restrict__ Wn2,
                               bf16* __restrict__ Wt1, bf16* __restrict__ Wt2) {
    int tid = blockIdx.x * 256 + threadIdx.x;
    if (tid < HDIM * K1) {
        int n = tid / K1, k = tid - n * K1;
        float v = (k < IN1) ? Ws1[k * HDIM + n] : Wn1[(k - IN1) * HDIM + n];
        Wt1[n * K1 + k] = (bf16)v;
    } else {
        int t2 = tid - HDIM * K1;
        int n = t2 / K2, k = t2 - n * K2;
        float v = (k < HDIM) ? Ws2[k * HDIM + n] : Wn2[(k - HDIM) * HDIM + n];
        Wt2[n * K2 + k] = (bf16)v;
    }
}

// ---------------- CSR build ----------------
__global__ void k_count(const int* __restrict__ dst, int* __restrict__ deg) {
    int e = blockIdx.x * 256 + threadIdx.x;
    if (e < N_EDGES) atomicAdd(&deg[dst[e]], 1);
}

// block-inclusive Hillis-Steele scan over `lds`, returns inclusive prefix of v
template <int NT>
__device__ __forceinline__ int block_scan_inc(int v, int* lds) {
    int tid = threadIdx.x;
    lds[tid] = v;
#pragma unroll
    for (int off = 1; off < NT; off <<= 1) {
        __syncthreads();
        int t = (tid >= off) ? lds[tid - off] : 0;
        __syncthreads();
        lds[tid] += t;
    }
    return lds[tid];
}

__global__ void k_scanA(const int* __restrict__ deg, int* __restrict__ presum,
                        int* __restrict__ part) {
    __shared__ int lds[256];
    int idx = blockIdx.x * 256 + threadIdx.x;
    int v = (idx < N_NODES) ? deg[idx] : 0;
    int inc = block_scan_inc<256>(v, lds);
    presum[idx] = inc - v;
    if (threadIdx.x == 255) part[blockIdx.x] = inc;
}

__global__ void k_scanB(int* __restrict__ part) {
    __shared__ int lds[512];
    int t = threadIdx.x;
    int v = (t < NB) ? part[t] : 0;
    int inc = block_scan_inc<512>(v, lds);
    if (t < NB) part[t] = inc - v;   // exclusive
}

__global__ void k_scanC(const int* __restrict__ presum, const int* __restrict__ part,
                        int* __restrict__ rowptr, int* __restrict__ cursor) {
    int idx = blockIdx.x * 256 + threadIdx.x;
    int v = presum[idx] + part[blockIdx.x];
    if (idx < N_NODES) { rowptr[idx] = v; cursor[idx] = v; }
}

__global__ void k_fill(const int* __restrict__ src, const int* __restrict__ dst,
                       int* __restrict__ cursor, int2* __restrict__ csr) {
    int e = blockIdx.x * 256 + threadIdx.x;   // exact grid
    int p = atomicAdd(&cursor[dst[e]], 1);
    csr[p] = make_int2(src[e], e);
}

// ---------------- aggregation: one wave per node ----------------
// 16-deep MLP: lane i preloads csr[base+c+i] (one coalesced load per 64-edge
// chunk), then shfl-broadcast 16 eids and issue 16 INDEPENDENT gathers into
// distinct regs before any use. Predication (j<m) is wave-uniform -> scalar
// branches, no wasted gather issues.

// h1 row n, cols 0:128 = fn[n]; cols 128:176 = mean of fe over incoming edges
__global__ void k_agg_edges(const float* __restrict__ fn, const float* __restrict__ fe,
                            const int* __restrict__ rowptr, const int* __restrict__ deg,
                            const int2* __restrict__ csr, bf16* __restrict__ h1) {
    int node = blockIdx.x * 4 + (threadIdx.x >> 6);  // grid 25000 exact
    int lane = threadIdx.x & 63;
    bf16* row = h1 + (size_t)node * K1;
    float2 f = *(const float2*)(fn + (size_t)node * DN + lane * 2);
    *(unsigned*)&row[lane * 2] = bf_pk(f.x, f.y);
    int base = rowptr[node], d = deg[node];
    float s = 0.f;
    for (int c = 0; c < d; c += 64) {
        int nn = min(d - c, 64);
        int myE = (lane < nn) ? csr[base + c + lane].y : 0;
        for (int i = 0; i < nn; i += 16) {
            int m = min(nn - i, 16);
            int e[16];
#pragma unroll
            for (int j = 0; j < 16; ++j) e[j] = __shfl(myE, i + j);
            float v[16];
#pragma unroll
            for (int j = 0; j < 16; ++j) {
                v[j] = 0.f;
                if (j < m && lane < DE)
                    v[j] = fe[(size_t)e[j] * DE + lane];
            }
            float t0 = ((v[0] + v[1]) + (v[2] + v[3])) + ((v[4] + v[5]) + (v[6] + v[7]));
            float t1 = ((v[8] + v[9]) + (v[10] + v[11])) + ((v[12] + v[13]) + (v[14] + v[15]));
            s += t0 + t1;
        }
    }
    float r = 1.0f / (float)max(d, 1);
    if (lane < DE) row[DN + lane] = (bf16)(s * r);
}

// h1 cols 176:352 = mean over incoming edges of h1[src, 0:176]
// 176 bf16 cols = 44 lanes x uint2 (one 8B load/edge)
__global__ void k_agg1(const int* __restrict__ rowptr, const int* __restrict__ deg,
                       const int2* __restrict__ csr, bf16* __restrict__ h1) {
    int node = blockIdx.x * 4 + (threadIdx.x >> 6);
    int lane = threadIdx.x & 63;
    int base = rowptr[node], d = deg[node];
    float s0 = 0.f, s1 = 0.f, s2 = 0.f, s3 = 0.f;
    for (int c = 0; c < d; c += 64) {
        int nn = min(d - c, 64);
        int mySv = (lane < nn) ? csr[base + c + lane].x : 0;
        for (int i = 0; i < nn; i += 16) {
            int m = min(nn - i, 16);
            int sv[16];
#pragma unroll
            for (int j = 0; j < 16; ++j) sv[j] = __shfl(mySv, i + j);
            uint2 u[16];
#pragma unroll
            for (int j = 0; j < 16; ++j) {
                u[j] = make_uint2(0u, 0u);
                if (j < m && lane < 44)
                    u[j] = ((const uint2*)(h1 + (size_t)sv[j] * K1))[lane];
            }
#pragma unroll
            for (int j = 0; j < 16; ++j) {
                s0 += bf_lo(u[j].x); s1 += bf_hi(u[j].x);
                s2 += bf_lo(u[j].y); s3 += bf_hi(u[j].y);
            }
        }
    }
    float r = 1.0f / (float)max(d, 1);
    if (lane < 44) {
        uint2 o;
        o.x = bf_pk(s0 * r, s1 * r);
        o.y = bf_pk(s2 * r, s3 * r);
        ((uint2*)(h1 + (size_t)node * K1 + IN1))[lane] = o;
    }
}

// h2 cols 256:512 = mean over incoming edges of h2[src, 0:256]
__global__ void k_agg2(const int* __restrict__ rowptr, const int* __restrict__ deg,
                       const int2* __restrict__ csr, bf16* __restrict__ h2) {
    int node = blockIdx.x * 4 + (threadIdx.x >> 6);
    int lane = threadIdx.x & 63;
    int base = rowptr[node], d = deg[node];
    float s0 = 0.f, s1 = 0.f, s2 = 0.f, s3 = 0.f;
    for (int c = 0; c < d; c += 64) {
        int nn = min(d - c, 64);
        int mySv = (lane < nn) ? csr[base + c + lane].x : 0;
        for (int i = 0; i < nn; i += 16) {
            int m = min(nn - i, 16);
            int sv[16];
#pragma unroll
            for (int j = 0; j < 16; ++j) sv[j] = __shfl(mySv, i + j);
            uint2 u[16];
#pragma unroll
            for (int j = 0; j < 16; ++j) {
                u[j] = make_uint2(0u, 0u);
                if (j < m)
                    u[j] = ((const uint2*)(h2 + (size_t)sv[j] * K2))[lane];
            }
#pragma unroll
            for (int j = 0; j < 16; ++j) {
                s0 += bf_lo(u[j].x); s1 += bf_hi(u[j].x);
                s2 += bf_lo(u[j].y); s3 += bf_hi(u[j].y);
            }
        }
    }
    float r = 1.0f / (float)max(d, 1);
    uint2 o;
    o.x = bf_pk(s0 * r, s1 * r);
    o.y = bf_pk(s2 * r, s3 * r);
    ((uint2*)(h2 + (size_t)node * K2 + HDIM))[lane] = o;
}

// ---------------- bf16 MFMA GEMM: C[NPAD,256] = A[NPAD,K] @ Wt^T + bias ----------------
// 2-phase prefetch: store current tile regs -> LDS, issue next-tile global
// loads, then ds_read+MFMA. vmcnt wait for the prefetch lands at the NEXT
// iteration's LDS store, so staging latency hides under a full MFMA phase.
template <bool RELU, typename OT>
__global__ __launch_bounds__(256) void k_gemm(const bf16* __restrict__ A,
                                              const bf16* __restrict__ Wt,
                                              const float* __restrict__ bias,
                                              OT* __restrict__ out,
                                              int Ktiles, int ostride) {
    __shared__ __align__(16) bf16 lA[128 * 40];
    __shared__ __align__(16) bf16 lB[128 * 40];

    const int tid = threadIdx.x;
    const int rowBase = blockIdx.x * 128;
    const int colBase = blockIdx.y * 128;
    const int l = tid & 63, w = tid >> 6;
    const int wr = (w >> 1) * 64, wc = (w & 1) * 64;
    const int lm = l & 15, lq = l >> 4;
    const int K = Ktiles * 32;

    const int srow = tid >> 1;
    const int sko  = (tid & 1) * 16;

    const bf16* pA = A  + (size_t)(rowBase + srow) * K + sko;
    const bf16* pB = Wt + (size_t)(colBase + srow) * K + sko;

    f32x4 acc[4][4] = {};

    uint4 a0 = *(const uint4*)(pA), a1 = *(const uint4*)(pA + 8);
    uint4 b0 = *(const uint4*)(pB), b1 = *(const uint4*)(pB + 8);

    for (int kt = 0; kt < Ktiles; ++kt) {
        __syncthreads();   // previous iteration's ds_reads done
        *(uint4*)&lA[srow * 40 + sko]     = a0;
        *(uint4*)&lA[srow * 40 + sko + 8] = a1;
        *(uint4*)&lB[srow * 40 + sko]     = b0;
        *(uint4*)&lB[srow * 40 + sko + 8] = b1;
        __syncthreads();

        if (kt + 1 < Ktiles) {   // wave-uniform
            pA += 32; pB += 32;
            a0 = *(const uint4*)(pA); a1 = *(const uint4*)(pA + 8);
            b0 = *(const uint4*)(pB); b1 = *(const uint4*)(pB + 8);
        }

        bf16x8 af[4], bfr[4];
#pragma unroll
        for (int mi = 0; mi < 4; ++mi)
            af[mi] = *(const bf16x8*)&lA[(wr + mi * 16 + lm) * 40 + lq * 8];
#pragma unroll
        for (int ni = 0; ni < 4; ++ni)
            bfr[ni] = *(const bf16x8*)&lB[(wc + ni * 16 + lm) * 40 + lq * 8];
#pragma unroll
        for (int mi = 0; mi < 4; ++mi)
#pragma unroll
            for (int ni = 0; ni < 4; ++ni)
                acc[mi][ni] = __builtin_amdgcn_mfma_f32_16x16x32_bf16(
                    af[mi], bfr[ni], acc[mi][ni], 0, 0, 0);
    }

#pragma unroll
    for (int ni = 0; ni < 4; ++ni) {
        const int gcol = colBase + wc + ni * 16 + lm;
        const float bv = bias[gcol];
#pragma unroll
        for (int mi = 0; mi < 4; ++mi) {
#pragma unroll
            for (int r = 0; r < 4; ++r) {
                const int grow = rowBase + wr + mi * 16 + lq * 4 + r;
                if (grow < N_NODES) {
                    float v = acc[mi][ni][r] + bv;
                    if (RELU) v = fmaxf(v, 0.0f);
                    out[(size_t)grow * ostride + gcol] = (OT)v;
                }
            }
        }
    }
}

// ---------------- launcher ----------------
extern "C" void kernel_launch(void* const* d_in, const int* in_sizes, int n_in,
                              void* d_out, int out_size, void* d_ws, size_t ws_size,
                              hipStream_t stream) {
    const float* fn  = (const float*)d_in[0];
    const float* fe  = (const float*)d_in[1];
    const int*   src = (const int*)d_in[2];
    const int*   dst = (const int*)d_in[3];
    const float* Ws1 = (const float*)d_in[4];
    const float* Wn1 = (const float*)d_in[5];
    const float* b1  = (const float*)d_in[6];
    const float* Ws2 = (const float*)d_in[7];
    const float* Wn2 = (const float*)d_in[8];
    const float* b2  = (const float*)d_in[9];
    float* out = (float*)d_out;

    char* ws = (char*)d_ws;
    int*  deg    = (int*)(ws + O_DEG);
    int*  rowptr = (int*)(ws + O_ROW);
    int*  cursor = (int*)(ws + O_CUR);
    int*  presum = (int*)(ws + O_PRE);
    int*  part   = (int*)(ws + O_PART);
    int2* csr    = (int2*)(ws + O_CSR);
    bf16* h1  = (bf16*)(ws + O_H1);
    bf16* h2  = (bf16*)(ws + O_H2);
    bf16* Wt1 = (bf16*)(ws + O_W1);
    bf16* Wt2 = (bf16*)(ws + O_W2);

    hipMemsetAsync(deg, 0, (size_t)NPAD * 4, stream);
    hipMemsetAsync((char*)h1 + (size_t)N_NODES * K1 * 2, 0, (size_t)(NPAD - N_NODES) * K1 * 2, stream);
    hipMemsetAsync((char*)h2 + (size_t)N_NODES * K2 * 2, 0, (size_t)(NPAD - N_NODES) * K2 * 2, stream);

    k_prep_weights<<<(HDIM * K1 + HDIM * K2) / 256, 256, 0, stream>>>(Ws1, Wn1, Ws2, Wn2, Wt1, Wt2);

    // CSR build
    k_count<<<(N_EDGES + 255) / 256, 256, 0, stream>>>(dst, deg);
    k_scanA<<<NB, 256, 0, stream>>>(deg, presum, part);
    k_scanB<<<1, 512, 0, stream>>>(part);
    k_scanC<<<NB, 256, 0, stream>>>(presum, part, rowptr, cursor);
    k_fill<<<N_EDGES / 256, 256, 0, stream>>>(src, dst, cursor, csr);

    // layer 1
    k_agg_edges<<<N_NODES / 4, 256, 0, stream>>>(fn, fe, rowptr, deg, csr, h1);
    k_agg1<<<N_NODES / 4, 256, 0, stream>>>(rowptr, deg, csr, h1);
    k_gemm<true, bf16><<<dim3(NPAD / 128, 2), 256, 0, stream>>>(h1, Wt1, b1, h2, K1 / 32, K2);

    // layer 2
    k_agg2<<<N_NODES / 4, 256, 0, stream>>>(rowptr, deg, csr, h2);
    k_gemm<false, float><<<dim3(NPAD / 128, 2), 256, 0, stream>>>(h2, Wt2, b2, out, K2 / 32, HDIM);
}

// Round 3
// 1031.834 us; speedup vs baseline: 1.3271x; 1.0233x over previous
//
#include <hip/hip_runtime.h>

// ---------------- problem constants ----------------
#define N_NODES 100000
#define N_EDGES 1600000
#define DN 128
#define DE 48
#define HDIM 256
#define IN1 176            // DN + DE
#define K1 352             // 2*IN1  (concat [h | h_neigh] for layer 1)
#define K2 512             // 2*HDIM (concat [h1 | h_neigh] for layer 2)
#define NPAD 100096        // 782 * 128 (GEMM row padding; also 391*256 scan width)
#define NB 391             // scan blocks = NPAD/256

typedef __bf16 bf16;
typedef __bf16 bf16x2 __attribute__((ext_vector_type(2)));
typedef __bf16 bf16x8 __attribute__((ext_vector_type(8)));
typedef float  f32x4  __attribute__((ext_vector_type(4)));

// ---------------- workspace layout (bytes) ----------------
#define O_DEG  0UL                      // NPAD int
#define O_ROW  400384UL                 // NPAD int (rowptr)
#define O_CUR  800768UL                 // NPAD int (fill cursor)
#define O_PRE  1201152UL                // NPAD int (block-local prefix)
#define O_PART 1601536UL                // 512 int (block partials)
#define O_CSR  1603584UL                // E int2 (src, eid) = 12.8 MB
#define O_H1   14403584UL               // NPAD x 352 bf16 = 70.5 MB
#define O_H2   84871168UL               // NPAD x 512 bf16 = 102.5 MB
#define O_W1   187369472UL              // 256 x 352 bf16
#define O_W2   187549696UL              // 256 x 512 bf16; end ~188 MB

__device__ __forceinline__ float bf_lo(unsigned u) { return __uint_as_float(u << 16); }
__device__ __forceinline__ float bf_hi(unsigned u) { return __uint_as_float(u & 0xffff0000u); }
__device__ __forceinline__ unsigned bf_pk(float a, float b) {
    union { bf16x2 v; unsigned u; } t;
    t.v.x = (bf16)a; t.v.y = (bf16)b;
    return t.u;
}

// ---------------- weight prep: bf16, transposed to [n][k], self/neigh stacked in k ----------------
__global__ void k_prep_weights(const float* __restrict__ Ws1, const float* __restrict__ Wn1,
                               const float* __restrict__ Ws2, const float* __restrict__ Wn2,
                               bf16* __restrict__ Wt1, bf16* __restrict__ Wt2) {
    int tid = blockIdx.x * 256 + threadIdx.x;
    if (tid < HDIM * K1) {
        int n = tid / K1, k = tid - n * K1;
        float v = (k < IN1) ? Ws1[k * HDIM + n] : Wn1[(k - IN1) * HDIM + n];
        Wt1[n * K1 + k] = (bf16)v;
    } else {
        int t2 = tid - HDIM * K1;
        int n = t2 / K2, k = t2 - n * K2;
        float v = (k < HDIM) ? Ws2[k * HDIM + n] : Wn2[(k - HDIM) * HDIM + n];
        Wt2[n * K2 + k] = (bf16)v;
    }
}

// ---------------- CSR build ----------------
__global__ void k_count(const int* __restrict__ dst, int* __restrict__ deg) {
    int e = blockIdx.x * 256 + threadIdx.x;
    if (e < N_EDGES) atomicAdd(&deg[dst[e]], 1);
}

// block-inclusive Hillis-Steele scan over `lds`, returns inclusive prefix of v
template <int NT>
__device__ __forceinline__ int block_scan_inc(int v, int* lds) {
    int tid = threadIdx.x;
    lds[tid] = v;
#pragma unroll
    for (int off = 1; off < NT; off <<= 1) {
        __syncthreads();
        int t = (tid >= off) ? lds[tid - off] : 0;
        __syncthreads();
        lds[tid] += t;
    }
    return lds[tid];
}

__global__ void k_scanA(const int* __restrict__ deg, int* __restrict__ presum,
                        int* __restrict__ part) {
    __shared__ int lds[256];
    int idx = blockIdx.x * 256 + threadIdx.x;
    int v = (idx < N_NODES) ? deg[idx] : 0;
    int inc = block_scan_inc<256>(v, lds);
    presum[idx] = inc - v;
    if (threadIdx.x == 255) part[blockIdx.x] = inc;
}

__global__ void k_scanB(int* __restrict__ part) {
    __shared__ int lds[512];
    int t = threadIdx.x;
    int v = (t < NB) ? part[t] : 0;
    int inc = block_scan_inc<512>(v, lds);
    if (t < NB) part[t] = inc - v;   // exclusive
}

__global__ void k_scanC(const int* __restrict__ presum, const int* __restrict__ part,
                        int* __restrict__ rowptr, int* __restrict__ cursor) {
    int idx = blockIdx.x * 256 + threadIdx.x;
    int v = presum[idx] + part[blockIdx.x];
    if (idx < N_NODES) { rowptr[idx] = v; cursor[idx] = v; }
}

__global__ void k_fill(const int* __restrict__ src, const int* __restrict__ dst,
                       int* __restrict__ cursor, int2* __restrict__ csr) {
    int e = blockIdx.x * 256 + threadIdx.x;   // exact grid
    int p = atomicAdd(&cursor[dst[e]], 1);
    csr[p] = make_int2(src[e], e);
}

// ---------------- aggregation: one wave per node ----------------
// 16 B/lane multi-edge gathers: pack 2-4 edges into each wave-level load
// (dwordx4, full coalescing sweet spot), keep 8 independent loads in flight,
// then a 1-3 step __shfl cross-slot reduce merges per-slot partials.

// h1 row n, cols 0:128 = fn[n]; cols 128:176 = mean of fe over incoming edges
// fe row = 192 B = 12 lanes x float4; 4 edges per wave-load (48 lanes active)
__global__ void k_agg_edges(const float* __restrict__ fn, const float* __restrict__ fe,
                            const int* __restrict__ rowptr, const int* __restrict__ deg,
                            const int2* __restrict__ csr, bf16* __restrict__ h1) {
    int node = blockIdx.x * 4 + (threadIdx.x >> 6);  // grid 25000 exact
    int lane = threadIdx.x & 63;
    bf16* row = h1 + (size_t)node * K1;
    float2 f = *(const float2*)(fn + (size_t)node * DN + lane * 2);
    *(unsigned*)&row[lane * 2] = bf_pk(f.x, f.y);
    int base = rowptr[node], d = deg[node];
    int slot = lane / 12;           // 0..3 active, 4-5 idle
    int sub  = lane - slot * 12;    // float4 index within the 192 B row
    bool act = lane < 48;
    f32x4 s = {0.f, 0.f, 0.f, 0.f};
    for (int c = 0; c < d; c += 64) {
        int nn = min(d - c, 64);
        int myE = (lane < nn) ? csr[base + c + lane].y : 0;
        for (int i = 0; i < nn; i += 16) {
            f32x4 v[4];
#pragma unroll
            for (int g = 0; g < 4; ++g) {
                int ei = i + g * 4 + slot;
                int e = __shfl(myE, ei);
                v[g] = (f32x4){0.f, 0.f, 0.f, 0.f};
                if (act && ei < nn)
                    v[g] = *(const f32x4*)(fe + (size_t)e * DE + sub * 4);
            }
            s += (v[0] + v[1]) + (v[2] + v[3]);
        }
    }
    // merge the 4 edge-slots onto lanes 0-11 (same col-chunk: sub == lane)
#pragma unroll
    for (int k = 0; k < 4; ++k) {
        float t = s[k];
        t += __shfl(s[k], lane + 12);
        t += __shfl(s[k], lane + 24);
        t += __shfl(s[k], lane + 36);
        s[k] = t;
    }
    if (lane < 12) {
        float r = 1.0f / (float)max(d, 1);
        uint2 o;
        o.x = bf_pk(s[0] * r, s[1] * r);
        o.y = bf_pk(s[2] * r, s[3] * r);
        *((uint2*)(row + DN) + lane) = o;
    }
}

// h1 cols 176:352 = mean over incoming edges of h1[src, 0:176]
// 352 B row = 22 lanes x dwordx4; 2 edges per wave-load (44 lanes active)
__global__ void k_agg1(const int* __restrict__ rowptr, const int* __restrict__ deg,
                       const int2* __restrict__ csr, bf16* __restrict__ h1) {
    int node = blockIdx.x * 4 + (threadIdx.x >> 6);
    int lane = threadIdx.x & 63;
    int base = rowptr[node], d = deg[node];
    int slot = (lane < 22) ? 0 : ((lane < 44) ? 1 : 2);
    int sub  = lane - slot * 22;
    bool act = lane < 44;
    float s0 = 0.f, s1 = 0.f, s2 = 0.f, s3 = 0.f, s4 = 0.f, s5 = 0.f, s6 = 0.f, s7 = 0.f;
    for (int c = 0; c < d; c += 64) {
        int nn = min(d - c, 64);
        int mySv = (lane < nn) ? csr[base + c + lane].x : 0;
        for (int i = 0; i < nn; i += 16) {
            uint4 q[8];
#pragma unroll
            for (int g = 0; g < 8; ++g) {
                int ei = i + g * 2 + slot;
                int sv = __shfl(mySv, ei);
                q[g] = make_uint4(0u, 0u, 0u, 0u);
                if (act && ei < nn)
                    q[g] = *((const uint4*)(h1 + (size_t)sv * K1) + sub);
            }
#pragma unroll
            for (int g = 0; g < 8; ++g) {
                s0 += bf_lo(q[g].x); s1 += bf_hi(q[g].x);
                s2 += bf_lo(q[g].y); s3 += bf_hi(q[g].y);
                s4 += bf_lo(q[g].z); s5 += bf_hi(q[g].z);
                s6 += bf_lo(q[g].w); s7 += bf_hi(q[g].w);
            }
        }
    }
    // merge slot 1 into slot 0 (lanes 0-21; same col-chunk: sub == lane)
    s0 += __shfl(s0, lane + 22); s1 += __shfl(s1, lane + 22);
    s2 += __shfl(s2, lane + 22); s3 += __shfl(s3, lane + 22);
    s4 += __shfl(s4, lane + 22); s5 += __shfl(s5, lane + 22);
    s6 += __shfl(s6, lane + 22); s7 += __shfl(s7, lane + 22);
    if (lane < 22) {
        float r = 1.0f / (float)max(d, 1);
        uint4 o;
        o.x = bf_pk(s0 * r, s1 * r);
        o.y = bf_pk(s2 * r, s3 * r);
        o.z = bf_pk(s4 * r, s5 * r);
        o.w = bf_pk(s6 * r, s7 * r);
        *((uint4*)(h1 + (size_t)node * K1 + IN1) + lane) = o;
    }
}

// h2 cols 256:512 = mean over incoming edges of h2[src, 0:256]
// 512 B row = 32 lanes x dwordx4; 2 edges per wave-load (64 lanes active)
__global__ void k_agg2(const int* __restrict__ rowptr, const int* __restrict__ deg,
                       const int2* __restrict__ csr, bf16* __restrict__ h2) {
    int node = blockIdx.x * 4 + (threadIdx.x >> 6);
    int lane = threadIdx.x & 63;
    int base = rowptr[node], d = deg[node];
    int half = lane >> 5, sub = lane & 31;
    float s0 = 0.f, s1 = 0.f, s2 = 0.f, s3 = 0.f, s4 = 0.f, s5 = 0.f, s6 = 0.f, s7 = 0.f;
    for (int c = 0; c < d; c += 64) {
        int nn = min(d - c, 64);
        int mySv = (lane < nn) ? csr[base + c + lane].x : 0;
        for (int i = 0; i < nn; i += 16) {
            uint4 q[8];
#pragma unroll
            for (int g = 0; g < 8; ++g) {
                int ei = i + g * 2 + half;
                int sv = __shfl(mySv, ei);
                q[g] = make_uint4(0u, 0u, 0u, 0u);
                if (ei < nn)
                    q[g] = *((const uint4*)(h2 + (size_t)sv * K2) + sub);
            }
#pragma unroll
            for (int g = 0; g < 8; ++g) {
                s0 += bf_lo(q[g].x); s1 += bf_hi(q[g].x);
                s2 += bf_lo(q[g].y); s3 += bf_hi(q[g].y);
                s4 += bf_lo(q[g].z); s5 += bf_hi(q[g].z);
                s6 += bf_lo(q[g].w); s7 += bf_hi(q[g].w);
            }
        }
    }
    // merge halves (lane^32 has the same sub -> same col-chunk)
    s0 += __shfl(s0, lane ^ 32); s1 += __shfl(s1, lane ^ 32);
    s2 += __shfl(s2, lane ^ 32); s3 += __shfl(s3, lane ^ 32);
    s4 += __shfl(s4, lane ^ 32); s5 += __shfl(s5, lane ^ 32);
    s6 += __shfl(s6, lane ^ 32); s7 += __shfl(s7, lane ^ 32);
    if (half == 0) {
        float r = 1.0f / (float)max(d, 1);
        uint4 o;
        o.x = bf_pk(s0 * r, s1 * r);
        o.y = bf_pk(s2 * r, s3 * r);
        o.z = bf_pk(s4 * r, s5 * r);
        o.w = bf_pk(s6 * r, s7 * r);
        *((uint4*)(h2 + (size_t)node * K2 + HDIM) + sub) = o;
    }
}

// ---------------- bf16 MFMA GEMM: C[NPAD,256] = A[NPAD,K] @ Wt^T + bias ----------------
template <bool RELU, typename OT>
__global__ __launch_bounds__(256) void k_gemm(const bf16* __restrict__ A,
                                              const bf16* __restrict__ Wt,
                                              const float* __restrict__ bias,
                                              OT* __restrict__ out,
                                              int Ktiles, int ostride) {
    __shared__ __align__(16) bf16 lA[128 * 40];
    __shared__ __align__(16) bf16 lB[128 * 40];

    const int tid = threadIdx.x;
    const int rowBase = blockIdx.x * 128;
    const int colBase = blockIdx.y * 128;
    const int l = tid & 63, w = tid >> 6;
    const int wr = (w >> 1) * 64, wc = (w & 1) * 64;
    const int lm = l & 15, lq = l >> 4;
    const int K = Ktiles * 32;

    const int srow = tid >> 1;
    const int sko  = (tid & 1) * 16;

    const bf16* pA = A  + (size_t)(rowBase + srow) * K + sko;
    const bf16* pB = Wt + (size_t)(colBase + srow) * K + sko;

    f32x4 acc[4][4] = {};

    uint4 a0 = *(const uint4*)(pA), a1 = *(const uint4*)(pA + 8);
    uint4 b0 = *(const uint4*)(pB), b1 = *(const uint4*)(pB + 8);

    for (int kt = 0; kt < Ktiles; ++kt) {
        __syncthreads();   // previous iteration's ds_reads done
        *(uint4*)&lA[srow * 40 + sko]     = a0;
        *(uint4*)&lA[srow * 40 + sko + 8] = a1;
        *(uint4*)&lB[srow * 40 + sko]     = b0;
        *(uint4*)&lB[srow * 40 + sko + 8] = b1;
        __syncthreads();

        if (kt + 1 < Ktiles) {   // wave-uniform
            pA += 32; pB += 32;
            a0 = *(const uint4*)(pA); a1 = *(const uint4*)(pA + 8);
            b0 = *(const uint4*)(pB); b1 = *(const uint4*)(pB + 8);
        }

        bf16x8 af[4], bfr[4];
#pragma unroll
        for (int mi = 0; mi < 4; ++mi)
            af[mi] = *(const bf16x8*)&lA[(wr + mi * 16 + lm) * 40 + lq * 8];
#pragma unroll
        for (int ni = 0; ni < 4; ++ni)
            bfr[ni] = *(const bf16x8*)&lB[(wc + ni * 16 + lm) * 40 + lq * 8];
#pragma unroll
        for (int mi = 0; mi < 4; ++mi)
#pragma unroll
            for (int ni = 0; ni < 4; ++ni)
                acc[mi][ni] = __builtin_amdgcn_mfma_f32_16x16x32_bf16(
                    af[mi], bfr[ni], acc[mi][ni], 0, 0, 0);
    }

#pragma unroll
    for (int ni = 0; ni < 4; ++ni) {
        const int gcol = colBase + wc + ni * 16 + lm;
        const float bv = bias[gcol];
#pragma unroll
        for (int mi = 0; mi < 4; ++mi) {
#pragma unroll
            for (int r = 0; r < 4; ++r) {
                const int grow = rowBase + wr + mi * 16 + lq * 4 + r;
                if (grow < N_NODES) {
                    float v = acc[mi][ni][r] + bv;
                    if (RELU) v = fmaxf(v, 0.0f);
                    out[(size_t)grow * ostride + gcol] = (OT)v;
                }
            }
        }
    }
}

// ---------------- launcher ----------------
extern "C" void kernel_launch(void* const* d_in, const int* in_sizes, int n_in,
                              void* d_out, int out_size, void* d_ws, size_t ws_size,
                              hipStream_t stream) {
    const float* fn  = (const float*)d_in[0];
    const float* fe  = (const float*)d_in[1];
    const int*   src = (const int*)d_in[2];
    const int*   dst = (const int*)d_in[3];
    const float* Ws1 = (const float*)d_in[4];
    const float* Wn1 = (const float*)d_in[5];
    const float* b1  = (const float*)d_in[6];
    const float* Ws2 = (const float*)d_in[7];
    const float* Wn2 = (const float*)d_in[8];
    const float* b2  = (const float*)d_in[9];
    float* out = (float*)d_out;

    char* ws = (char*)d_ws;
    int*  deg    = (int*)(ws + O_DEG);
    int*  rowptr = (int*)(ws + O_ROW);
    int*  cursor = (int*)(ws + O_CUR);
    int*  presum = (int*)(ws + O_PRE);
    int*  part   = (int*)(ws + O_PART);
    int2* csr    = (int2*)(ws + O_CSR);
    bf16* h1  = (bf16*)(ws + O_H1);
    bf16* h2  = (bf16*)(ws + O_H2);
    bf16* Wt1 = (bf16*)(ws + O_W1);
    bf16* Wt2 = (bf16*)(ws + O_W2);

    hipMemsetAsync(deg, 0, (size_t)NPAD * 4, stream);
    hipMemsetAsync((char*)h1 + (size_t)N_NODES * K1 * 2, 0, (size_t)(NPAD - N_NODES) * K1 * 2, stream);
    hipMemsetAsync((char*)h2 + (size_t)N_NODES * K2 * 2, 0, (size_t)(NPAD - N_NODES) * K2 * 2, stream);

    k_prep_weights<<<(HDIM * K1 + HDIM * K2) / 256, 256, 0, stream>>>(Ws1, Wn1, Ws2, Wn2, Wt1, Wt2);

    // CSR build
    k_count<<<(N_EDGES + 255) / 256, 256, 0, stream>>>(dst, deg);
    k_scanA<<<NB, 256, 0, stream>>>(deg, presum, part);
    k_scanB<<<1, 512, 0, stream>>>(part);
    k_scanC<<<NB, 256, 0, stream>>>(presum, part, rowptr, cursor);
    k_fill<<<N_EDGES / 256, 256, 0, stream>>>(src, dst, cursor, csr);

    // layer 1
    k_agg_edges<<<N_NODES / 4, 256, 0, stream>>>(fn, fe, rowptr, deg, csr, h1);
    k_agg1<<<N_NODES / 4, 256, 0, stream>>>(rowptr, deg, csr, h1);
    k_gemm<true, bf16><<<dim3(NPAD / 128, 2), 256, 0, stream>>>(h1, Wt1, b1, h2, K1 / 32, K2);

    // layer 2
    k_agg2<<<N_NODES / 4, 256, 0, stream>>>(rowptr, deg, csr, h2);
    k_gemm<false, float><<<dim3(NPAD / 128, 2), 256, 0, stream>>>(h2, Wt2, b2, out, K2 / 32, HDIM);
}